// Round 17
// baseline (389.464 us; speedup 1.0000x reference)
//
#include <hip/hip_runtime.h>
#include <math.h>

#define NB 8
#define NC 128
#define NT 4096
#define NF 2049
#define FP 2176   // padded F = 17*128

typedef __bf16 bf16;
typedef __bf16 bf16x2 __attribute__((ext_vector_type(2)));
typedef __bf16 bf16x8 __attribute__((ext_vector_type(8)));
typedef float f32x4 __attribute__((ext_vector_type(4)));
typedef unsigned int uint32x4 __attribute__((ext_vector_type(4)));

// async global->LDS, 16 B per lane; lds dest must be wave-uniform base
__device__ __forceinline__ void async16(const bf16* g, bf16* l) {
    __builtin_amdgcn_global_load_lds(
        (const __attribute__((address_space(1))) void*)g,
        (__attribute__((address_space(3))) void*)l, 16, 0, 0);
}

// (Kr,-Ki) interleaved fragment -> (Ki,Kr): per dword swap halves, negate low
__device__ __forceinline__ bf16x8 derive_b2(bf16x8 v) {
    uint32x4 u = __builtin_bit_cast(uint32x4, v);
#pragma unroll
    for (int i = 0; i < 4; ++i)
        u[i] = (((u[i] >> 16) | (u[i] << 16)) ^ 0x00008000u);
    return __builtin_bit_cast(bf16x8, u);
}

__device__ __forceinline__ float2 cmulf(float2 a, float2 b) {
    return make_float2(a.x * b.x - a.y * b.y, a.x * b.y + a.y * b.x);
}

// fill LDS twiddle table: twl[k] = exp(-2*pi*i*k/4096), k in [0,2048)
__device__ __forceinline__ void fill_tw(float2* twl) {
    for (int k = threadIdx.x; k < 2048; k += 256) {
        float ang = (float)M_PI * (float)k * (1.0f / 2048.0f);
        float sw, cw;
        __sincosf(ang, &sw, &cw);
        twl[k] = make_float2(cw, -sw);
    }
}

// ---------------------------------------------------------------------------
// In-place radix-4 DIT FFT, length 4096 = 4^6, input base-4 digit-reversed.
// Twiddles from LDS table.
// ---------------------------------------------------------------------------
__device__ __forceinline__ void fft4096(float2* buf, const float2* twl) {
    int sh = 0;
#pragma unroll
    for (int s6 = 0; s6 < 6; ++s6) {
        int L = 1 << sh;
        __syncthreads();
        for (int t = threadIdx.x; t < 1024; t += 256) {
            int pos = t & (L - 1);
            int base = ((t >> sh) << (sh + 2)) + pos;
            int k1 = pos << (10 - sh);
            float2 w1 = twl[k1];
            float2 w2 = twl[2 * k1];
            float2 w3 = cmulf(w1, w2);
            float2 x0 = buf[base];
            float2 x1 = cmulf(buf[base + L], w1);
            float2 x2 = cmulf(buf[base + 2 * L], w2);
            float2 x3 = cmulf(buf[base + 3 * L], w3);
            float2 b0 = make_float2(x0.x + x2.x, x0.y + x2.y);
            float2 b1 = make_float2(x0.x - x2.x, x0.y - x2.y);
            float2 b2 = make_float2(x1.x + x3.x, x1.y + x3.y);
            float2 b3 = make_float2(x1.x - x3.x, x1.y - x3.y);
            buf[base]         = make_float2(b0.x + b2.x, b0.y + b2.y);
            buf[base + L]     = make_float2(b1.x + b3.y, b1.y - b3.x);  // b1 - i*b3
            buf[base + 2 * L] = make_float2(b0.x - b2.x, b0.y - b2.y);
            buf[base + 3 * L] = make_float2(b1.x - b3.y, b1.y + b3.x);  // b1 + i*b3
        }
        sh += 2;
    }
    __syncthreads();
}

// base-4 digit reversal of 12-bit index: bitrev then swap adjacent bits
__device__ __forceinline__ unsigned dr4(unsigned i) {
    unsigned r = __brev(i) >> 20;
    return ((r & 0x555u) << 1) | ((r & 0xAAAu) >> 1);
}

// ---------------------------------------------------------------------------
// Merged: rfft (blocks < NB*NC) + weight packing (blocks >= NB*NC).
// ---------------------------------------------------------------------------
__global__ __launch_bounds__(256) void fftfwd_kernel(const float* __restrict__ x_in,
                                                     const float* __restrict__ W_K,
                                                     const float* __restrict__ W_V,
                                                     float2* __restrict__ Xc,
                                                     bf16* __restrict__ Wk1,
                                                     bf16* __restrict__ Av) {
    __shared__ float2 buf[NT];
    __shared__ float2 twl[2048];
    int blk = blockIdx.x;
    if (blk >= NB * NC) {
        // weight packing: 256 blocks x 256 threads cover 65536 entries
        int idx = (blk - NB * NC) * 256 + threadIdx.x;
        int n = idx >> 8, k = idx & 255;
        int c = k >> 1;
        int j = n >> 1;
        float v = 0.f;
        if (!(n & 1) && !(k & 1)) v = W_K[j * NC + c];
        else if ((n & 1) && (k & 1)) v = -W_K[j * NC + c];
        Wk1[idx] = (bf16)v;
        float v2 = 0.f;
        if (!(n & 1) && !(k & 1)) v2 = W_V[j * NC + c];
        else if ((n & 1) && (k & 1)) v2 = W_V[j * NC + c];
        Av[idx] = (bf16)v2;
        return;
    }
    fill_tw(twl);
    const float* xrow = x_in + (size_t)blk * NT;
    for (int i = threadIdx.x; i < NT; i += 256)
        buf[dr4((unsigned)i)] = make_float2(xrow[i], 0.0f);
    fft4096(buf, twl);
    const float inv = 1.0f / 64.0f;
    float2* orow = Xc + (size_t)blk * NF;
    for (int f = threadIdx.x; f < NF; f += 256) {
        float2 v = buf[f];
        orow[f] = make_float2(v.x * inv, v.y * inv);
    }
}

// Transpose Xc (B,C,F) -> Xf (B,F,2C) fp32 + Xb (B,FP,256) bf16 (pad zero)
// + partial energy Ep[b][chalf][f].
__global__ __launch_bounds__(256) void xt_kernel(const float2* __restrict__ Xc,
                                                 float2* __restrict__ Xf2,
                                                 bf16* __restrict__ Xb,
                                                 float* __restrict__ Ep) {
    __shared__ float2 tile[64][65];
    int blk = blockIdx.x;
    int b = blk / 68;
    int t2 = blk % 68;
    int chalf = t2 / 34;
    int c0 = chalf * 64;
    int f0 = (t2 % 34) * 64;
    int t = threadIdx.x;
    int fl = t & 63, cc = t >> 6;
#pragma unroll
    for (int cb = 0; cb < 16; ++cb) {
        int cl = cb * 4 + cc;
        int f = f0 + fl;
        float2 v = make_float2(0.f, 0.f);
        if (f < NF) v = Xc[((size_t)b * NC + c0 + cl) * NF + f];
        tile[fl][cl] = v;
    }
    __syncthreads();
    int chl = t & 63, ww = t >> 6;
    float epart[16];
#pragma unroll
    for (int wb = 0; wb < 16; ++wb) {
        int fl2 = wb * 4 + ww;
        int f = f0 + fl2;
        float2 v = tile[fl2][chl];
        epart[wb] = v.x * v.x + v.y * v.y;
        if (f < NF) Xf2[((size_t)b * NF + f) * 128 + c0 + chl] = v;
        bf16x2 p;
        p[0] = (bf16)v.x; p[1] = (bf16)v.y;
        *(bf16x2*)&Xb[((size_t)b * FP + f) * 256 + 2 * (c0 + chl)] = p;
    }
    __syncthreads();
    float* es = (float*)tile;
#pragma unroll
    for (int wb = 0; wb < 16; ++wb)
        es[(wb * 4 + ww) * 65 + chl] = epart[wb];
    __syncthreads();
    if (t < 64 && f0 + t < NF) {
        float s = 0.f;
#pragma unroll
        for (int c = 0; c < 64; ++c) s += es[t * 65 + c];
        Ep[((size_t)b * 2 + chalf) * FP + f0 + t] = s;
    }
}

// ---------------------------------------------------------------------------
// GEMM body (128x128 tile, K=256, async staged)
// ---------------------------------------------------------------------------
__device__ __forceinline__ void gemm_body(const bf16* Abase, const bf16* Bbase,
                                          bf16* As, bf16* Bs,
                                          f32x4 (&acc)[4][4],
                                          int wave, int lane) {
    int m = lane & 15, quad = lane >> 4;
    int row_off = (wave & 1) * 64, col_off = (wave >> 1) * 64;
    int lrow = lane >> 3;
    int cswz = (lane & 7) ^ lrow;
    int mk = m & 7;
    for (int kk = 0; kk < 256; kk += 64) {
        __syncthreads();
#pragma unroll
        for (int t = 0; t < 4; ++t) {
            int r0 = wave * 32 + t * 8;
            async16(Abase + (size_t)(r0 + lrow) * 256 + kk + cswz * 8, As + r0 * 64);
            async16(Bbase + (size_t)(r0 + lrow) * 256 + kk + cswz * 8, Bs + r0 * 64);
        }
        __syncthreads();
#pragma unroll
        for (int k2 = 0; k2 < 64; k2 += 32) {
            bf16x8 a[4], bb[4];
            int pos = (((k2 >> 3) + quad) ^ mk) << 3;
#pragma unroll
            for (int i = 0; i < 4; ++i) a[i] = *(const bf16x8*)&As[(row_off + i * 16 + m) * 64 + pos];
#pragma unroll
            for (int j = 0; j < 4; ++j) bb[j] = *(const bf16x8*)&Bs[(col_off + j * 16 + m) * 64 + pos];
#pragma unroll
            for (int i = 0; i < 4; ++i)
#pragma unroll
                for (int j = 0; j < 4; ++j)
                    acc[i][j] = __builtin_amdgcn_mfma_f32_16x16x32_bf16(a[i], bb[j], acc[i][j], 0, 0, 0);
        }
    }
}

// ---------------------------------------------------------------------------
// Merged: K-proj GEMM (blk<272) | V-proj GEMM (272..543) | median (544..615)
// ---------------------------------------------------------------------------
__global__ __launch_bounds__(256, 2) void kvvt_med_kernel(const bf16* __restrict__ Xb,
                                                          const bf16* __restrict__ Wk1,
                                                          const bf16* __restrict__ Av,
                                                          const float* __restrict__ b_K,
                                                          const float* __restrict__ b_V,
                                                          const float* __restrict__ Ep,
                                                          bf16* __restrict__ K1,
                                                          bf16* __restrict__ Vt,
                                                          float* __restrict__ med) {
    __shared__ __align__(16) char smem[32768];
    bf16* As = (bf16*)smem;
    bf16* Bs = (bf16*)(smem + 16384);
    int blk = blockIdx.x;
    int tid = threadIdx.x;
    const int HALF = NB * 17 * 2;  // 272
    if (blk >= 2 * HALF) {
        // --- median: batch x 9 chunk blocks ---
        int mb = blk - 2 * HALF;
        int b = mb / 9, chunk = mb % 9;
        float* e = (float*)smem;  // 2052 floats = 8208 B
        const float* e0 = Ep + (size_t)b * 2 * FP;
        const float* e1 = e0 + FP;
        for (int i = tid; i < 2052; i += 256)
            e[i] = (i < NF) ? (e0[i] + e1[i]) : INFINITY;
        __syncthreads();
        int i = chunk * 256 + tid;
        float ei = (i < NF) ? e[i] : 0.f;
        int rank = 0;
#pragma unroll 4
        for (int j4 = 0; j4 < 513; ++j4) {
            float4 v = ((const float4*)e)[j4];
            int j = j4 * 4;
            rank += (v.x < ei) || (v.x == ei && j + 0 < i);
            rank += (v.y < ei) || (v.y == ei && j + 1 < i);
            rank += (v.z < ei) || (v.z == ei && j + 2 < i);
            rank += (v.w < ei) || (v.w == ei && j + 3 < i);
        }
        if (i < NF && rank == 1024) med[b] = ei;
        return;
    }
    int wave = tid >> 6, lane = tid & 63;
    int m = lane & 15, quad = lane >> 4;
    int row_off = (wave & 1) * 64, col_off = (wave >> 1) * 64;
    f32x4 acc[4][4] = {};
    if (blk < HALF) {
        // --- K projection ---
        int b = blk & 7;
        int t2 = blk >> 3;
        int g0 = (t2 >> 1) * 128;
        int n0 = (t2 & 1) * 128;
        gemm_body(Xb + ((size_t)b * FP + g0) * 256, Wk1 + (size_t)n0 * 256,
                  As, Bs, acc, wave, lane);
#pragma unroll
        for (int i = 0; i < 4; ++i)
#pragma unroll
            for (int j = 0; j < 4; ++j)
#pragma unroll
                for (int r = 0; r < 4; ++r) {
                    int row = g0 + row_off + i * 16 + quad * 4 + r;
                    int col = n0 + col_off + j * 16 + m;
                    float val = acc[i][j][r];
                    if (row == 0 && !(col & 1)) val += 64.0f * b_K[col >> 1];
                    K1[((size_t)b * FP + row) * 256 + col] = (bf16)val;
                }
    } else {
        // --- V projection (transposed output) ---
        int blk2 = blk - HALF;
        int b = blk2 & 7;
        int t2 = blk2 >> 3;
        int g0 = (t2 >> 1) * 128;
        int n0 = (t2 & 1) * 128;
        gemm_body(Av + (size_t)n0 * 256, Xb + ((size_t)b * FP + g0) * 256,
                  As, Bs, acc, wave, lane);
#pragma unroll
        for (int i = 0; i < 4; ++i)
#pragma unroll
            for (int j = 0; j < 4; ++j)
#pragma unroll
                for (int r = 0; r < 4; ++r) {
                    int row = n0 + row_off + i * 16 + quad * 4 + r;
                    int col = g0 + col_off + j * 16 + m;
                    float val = acc[i][j][r];
                    if (col == 0 && !(row & 1)) val += 64.0f * b_V[row >> 1];
                    Vt[((size_t)b * 256 + row) * FP + col] = (bf16)val;
                }
    }
}

// rankreduce: writes the two order statistics vk[0], vk[1]
__global__ __launch_bounds__(256) void rankreduce_kernel(const int* __restrict__ rankpart,
                                                         const float* __restrict__ nrm,
                                                         const float* __restrict__ q,
                                                         float* __restrict__ vk) {
    const int n = NB * NF;
    int i = blockIdx.x * 256 + threadIdx.x;
    if (i >= n) return;
    int rank = 0;
    const int* rp = rankpart + (size_t)i * 17;
#pragma unroll
    for (int c = 0; c < 17; ++c) rank += rp[c];
    double pos = (double)q[0] * (double)(n - 1);
    int k0 = (int)floor(pos);
    int k1 = min(k0 + 1, n - 1);
    if (rank == k0) vk[0] = nrm[i];
    if (rank == k1) vk[1] = nrm[i];
}

// ---------------------------------------------------------------------------
// Merged: scores (blk < NB*17*34) + norm/rankpart (rest).
// ---------------------------------------------------------------------------
__global__ __launch_bounds__(256, 4) void score_rank_kernel(const bf16* __restrict__ Xb,
                                                            const bf16* __restrict__ K1,
                                                            const float* __restrict__ Ep,
                                                            const float* __restrict__ med,
                                                            bf16* __restrict__ S,
                                                            float* __restrict__ Mpart,
                                                            float* __restrict__ Lpart,
                                                            float* __restrict__ nrm,
                                                            int* __restrict__ rankpart) {
    __shared__ __align__(16) char smem[24576];
    int blk = blockIdx.x;
    int tid = threadIdx.x;
    const int NSCORE = NB * 17 * 34;  // 4624
    if (blk >= NSCORE) {
        // --- norm + partial rank over one 1024-chunk ---
        const int n = NB * NF;
        int rb = blk - NSCORE;
        int cb = rb / 17;
        int chunk = rb % 17;
        float* cdata = (float*)smem;  // 4 KB
        int base = chunk * 1024;
        for (int t = tid; t < 1024; t += 256) {
            int idx = base + t;
            float v = INFINITY;
            if (idx < n) {
                int b = idx / NF, f = idx % NF;
                float e = Ep[((size_t)b * 2) * FP + f] + Ep[((size_t)b * 2 + 1) * FP + f];
                v = e / (med[b] + 1e-6f);
            }
            cdata[t] = v;
        }
        __syncthreads();
        int i = cb * 256 + tid;
        if (i >= n) return;
        int bi = i / NF, fi = i % NF;
        float ei = (Ep[((size_t)bi * 2) * FP + fi] + Ep[((size_t)bi * 2 + 1) * FP + fi]) /
                   (med[bi] + 1e-6f);
        if (chunk == 0) nrm[i] = ei;
        int rank = 0;
#pragma unroll 8
        for (int t4 = 0; t4 < 256; ++t4) {
            float4 v = ((const float4*)cdata)[t4];
            int j = base + t4 * 4;
            rank += (v.x < ei) || (v.x == ei && j + 0 < i);
            rank += (v.y < ei) || (v.y == ei && j + 1 < i);
            rank += (v.z < ei) || (v.z == ei && j + 2 < i);
            rank += (v.w < ei) || (v.w == ei && j + 3 < i);
        }
        rankpart[(size_t)i * 17 + chunk] = rank;
        return;
    }
    // --- score ---
    bf16* As  = (bf16*)smem;
    bf16* B1s = (bf16*)(smem + 16384);
    int b = blk & 7;
    int t2 = blk >> 3;
    int f0 = (t2 / 34) * 128;
    int gblk = t2 % 34;
    int g0 = gblk * 64;
    int wave = tid >> 6, lane = tid & 63;
    int m = lane & 15, quad = lane >> 4;
    int row_off = (wave & 1) * 64, col_off = (wave >> 1) * 32;

    f32x4 accRe[4][2] = {};
    f32x4 accIm[4][2] = {};
    const bf16* Abase = Xb + ((size_t)b * FP + f0) * 256;
    const bf16* Kbase = K1 + ((size_t)b * FP + g0) * 256;
    int lrow = lane >> 3;
    int cswz = (lane & 7) ^ lrow;
    int mk = m & 7;

    for (int kk = 0; kk < 256; kk += 64) {
        __syncthreads();
#pragma unroll
        for (int t = 0; t < 4; ++t) {
            int r0 = wave * 32 + t * 8;
            async16(Abase + (size_t)(r0 + lrow) * 256 + kk + cswz * 8, As + r0 * 64);
        }
#pragma unroll
        for (int t = 0; t < 2; ++t) {
            int r0 = wave * 16 + t * 8;
            async16(Kbase + (size_t)(r0 + lrow) * 256 + kk + cswz * 8, B1s + r0 * 64);
        }
        __syncthreads();
#pragma unroll
        for (int k2 = 0; k2 < 64; k2 += 32) {
            bf16x8 a[4], b1[2], b2[2];
            int pos = (((k2 >> 3) + quad) ^ mk) << 3;
#pragma unroll
            for (int i = 0; i < 4; ++i)
                a[i] = *(const bf16x8*)&As[(row_off + i * 16 + m) * 64 + pos];
#pragma unroll
            for (int j = 0; j < 2; ++j) {
                b1[j] = *(const bf16x8*)&B1s[(col_off + j * 16 + m) * 64 + pos];
                b2[j] = derive_b2(b1[j]);
            }
#pragma unroll
            for (int i = 0; i < 4; ++i)
#pragma unroll
                for (int j = 0; j < 2; ++j) {
                    accRe[i][j] = __builtin_amdgcn_mfma_f32_16x16x32_bf16(a[i], b1[j], accRe[i][j], 0, 0, 0);
                    accIm[i][j] = __builtin_amdgcn_mfma_f32_16x16x32_bf16(a[i], b2[j], accIm[i][j], 0, 0, 0);
                }
        }
    }
    const float SCALE = 0.08838834764831845f;  // 1/sqrt(128)
    __syncthreads();
    bf16 (*Cs)[76] = (bf16(*)[76])smem;
#pragma unroll
    for (int i = 0; i < 4; ++i)
#pragma unroll
        for (int j = 0; j < 2; ++j)
#pragma unroll
            for (int r = 0; r < 4; ++r) {
                float re = accRe[i][j][r], im = accIm[i][j][r];
                Cs[row_off + i * 16 + quad * 4 + r][col_off + j * 16 + m] =
                    (bf16)(sqrtf(re * re + im * im) * SCALE);
            }
    __syncthreads();
    float* mred = (float*)(smem + 19456);
    float* lred = (float*)(smem + 20480);
    bf16* Sb = S + (size_t)b * FP * FP;
    int row = tid >> 1, half = tid & 1;
    const bf16* src = &Cs[row][half * 32];
    bf16* dst = Sb + (size_t)(f0 + row) * FP + g0 + half * 32;
    int gbase = g0 + half * 32;
    float vf[32];
#pragma unroll
    for (int u = 0; u < 4; ++u) {
        bf16x8 v8 = *(const bf16x8*)&src[u * 8];
        *(bf16x8*)&dst[u * 8] = v8;
#pragma unroll
        for (int e = 0; e < 8; ++e) vf[u * 8 + e] = (float)v8[e];
    }
    if (gblk >= 32) {
#pragma unroll
        for (int k = 0; k < 32; ++k)
            if (gbase + k > 2048) vf[k] = -1e30f;
    }
    float lmax = -1e30f;
#pragma unroll
    for (int k = 0; k < 32; ++k) lmax = fmaxf(lmax, vf[k]);
    mred[tid] = lmax;
    __syncthreads();
    float rmax = fmaxf(mred[row * 2], mred[row * 2 + 1]);
    float lsum = 0.f;
#pragma unroll
    for (int k = 0; k < 32; ++k) lsum += __expf(vf[k] - rmax);
    lred[tid] = lsum;
    __syncthreads();
    if (half == 0) {
        size_t ro = ((size_t)b * FP + f0 + row) * 34 + gblk;
        Mpart[ro] = rmax;
        Lpart[ro] = lred[row * 2] + lred[row * 2 + 1];
    }
}

// ---------------------------------------------------------------------------
// Context + rowstat + thresh + hifreq + transpose fused.
// ---------------------------------------------------------------------------
__global__ __launch_bounds__(256, 3) void context_kernel(const bf16* __restrict__ Sg,
                                                         const float* __restrict__ Mpart,
                                                         const float* __restrict__ Lpart,
                                                         const bf16* __restrict__ Vt,
                                                         const float2* __restrict__ Xf2,
                                                         const float* __restrict__ nrm,
                                                         const float* __restrict__ vk,
                                                         const float* __restrict__ q,
                                                         const float* __restrict__ w_high,
                                                         float* __restrict__ Ctxt) {
    __shared__ __align__(16) char smem[36864];
    bf16* Ps = (bf16*)smem;              // 32*64 = 4 KB
    bf16* Vs = (bf16*)(smem + 4096);     // 256*64 = 32 KB
    int blk = blockIdx.x;
    int b = blk & 7;
    int f0 = (blk >> 3) * 32;
    int tid = threadIdx.x;
    int wave = tid >> 6, lane = tid & 63;
    int m = lane & 15, quad = lane >> 4;
    int col_off = wave * 64;
    int lrow = lane >> 3;
    int cswz = (lane & 7) ^ lrow;
    int mk = m & 7;

    f32x4 acc[2][4] = {};
    int prow = wave * 8 + lrow;  // 0..31
    const bf16* Prow = Sg + ((size_t)b * FP + f0 + prow) * FP;
    float cst;
    {
        const float* mp = Mpart + ((size_t)b * FP + f0 + prow) * 34;
        const float* lp = Lpart + ((size_t)b * FP + f0 + prow) * 34;
        float M = -1e30f;
#pragma unroll
        for (int i = 0; i < 34; ++i) M = fmaxf(M, mp[i]);
        float L = 0.f;
#pragma unroll
        for (int i = 0; i < 34; ++i) L += lp[i] * __expf(mp[i] - M);
        cst = M + __logf(L);
    }
    float thrv;
    {
        const int n = NB * NF;
        double pos = (double)q[0] * (double)(n - 1);
        double k0 = floor(pos);
        double frac = pos - k0;
        thrv = (float)((double)vk[0] + ((double)vk[1] - (double)vk[0]) * frac);
    }
    const bf16* Vbase = Vt + (size_t)b * 256 * FP;

    for (int kk = 0; kk < FP; kk += 64) {
        __syncthreads();
#pragma unroll
        for (int t = 0; t < 8; ++t) {
            int r0 = wave * 64 + t * 8;
            async16(Vbase + (size_t)(r0 + lrow) * FP + kk + cswz * 8, Vs + r0 * 64);
        }
        {
            bf16x8 s8 = *(const bf16x8*)&Prow[kk + cswz * 8];
            bf16x8 p8;
#pragma unroll
            for (int e = 0; e < 8; ++e) p8[e] = (bf16)__expf((float)s8[e] - cst);
            *(bf16x8*)&Ps[prow * 64 + (lane & 7) * 8] = p8;
        }
        __syncthreads();
#pragma unroll
        for (int k2 = 0; k2 < 64; k2 += 32) {
            bf16x8 a[2], bb[4];
            int pos = (((k2 >> 3) + quad) ^ mk) << 3;
#pragma unroll
            for (int i = 0; i < 2; ++i) a[i] = *(const bf16x8*)&Ps[(i * 16 + m) * 64 + pos];
#pragma unroll
            for (int j = 0; j < 4; ++j) bb[j] = *(const bf16x8*)&Vs[(col_off + j * 16 + m) * 64 + pos];
#pragma unroll
            for (int i = 0; i < 2; ++i)
#pragma unroll
                for (int j = 0; j < 4; ++j)
                    acc[i][j] = __builtin_amdgcn_mfma_f32_16x16x32_bf16(a[i], bb[j], acc[i][j], 0, 0, 0);
        }
    }
#pragma unroll
    for (int i = 0; i < 2; ++i)
#pragma unroll
        for (int r = 0; r < 4; ++r) {
            int row = f0 + i * 16 + quad * 4 + r;
            if (row < NF && nrm[b * NF + row] > thrv) {
#pragma unroll
                for (int j = 0; j < 4; ++j) {
                    int col = col_off + j * 16 + m;
                    int c = col >> 1;
                    float2 x = Xf2[((size_t)b * NF + row) * 128 + c];
                    float wr = w_high[2 * c], wi = w_high[2 * c + 1];
                    acc[i][j][r] += (col & 1) ? (x.x * wi + x.y * wr)
                                              : (x.x * wr - x.y * wi);
                }
            }
        }
    __syncthreads();
    float (*Ts)[33] = (float(*)[33])smem;
#pragma unroll
    for (int i = 0; i < 2; ++i)
#pragma unroll
        for (int j = 0; j < 4; ++j)
#pragma unroll
            for (int r = 0; r < 4; ++r) {
                int fl = i * 16 + quad * 4 + r;
                int col = col_off + j * 16 + m;
                Ts[col][fl] = acc[i][j][r];
            }
    __syncthreads();
    int f = tid & 31;
    int ch0 = tid >> 5;
    if (f0 + f < NF) {
#pragma unroll
        for (int p = 0; p < 32; ++p) {
            int ch = ch0 + p * 8;
            Ctxt[((size_t)b * 256 + ch) * NF + f0 + f] = Ts[ch][f];
        }
    }
}

// irfft (ortho) reading contiguous Ctxt rows; twiddles self-computed in LDS
__global__ __launch_bounds__(256) void fft_inv_kernel(const float* __restrict__ Ctxt,
                                                      float* __restrict__ out) {
    __shared__ float2 buf[NT];
    __shared__ float2 twl[2048];
    int bc = blockIdx.x, b = bc >> 7, c = bc & 127;
    fill_tw(twl);
    const float* base = Ctxt + ((size_t)b * 256 + 2 * c) * NF;
    const float* basei = base + NF;
    for (int f = threadIdx.x; f < NT; f += 256) {
        float re, im;
        if (f <= NT / 2) {
            re = base[f];
            im = -basei[f];
        } else {
            int g = NT - f;
            re = base[g];
            im = basei[g];
        }
        buf[dr4((unsigned)f)] = make_float2(re, im);
    }
    fft4096(buf, twl);
    float* orow = out + (size_t)bc * NT;
    const float inv = 1.0f / 64.0f;
    for (int n = threadIdx.x; n < NT; n += 256) orow[n] = buf[n].x * inv;
}

extern "C" void kernel_launch(void* const* d_in, const int* in_sizes, int n_in,
                              void* d_out, int out_size, void* d_ws, size_t ws_size,
                              hipStream_t stream) {
    const float* x_in = (const float*)d_in[0];
    const float* W_K = (const float*)d_in[1];
    const float* b_K = (const float*)d_in[2];
    const float* W_V = (const float*)d_in[3];
    const float* b_V = (const float*)d_in[4];
    const float* w_high = (const float*)d_in[5];
    const float* qpar = (const float*)d_in[6];
    float* out = (float*)d_out;

    char* w = (char*)d_ws;
    const size_t SPECB = (size_t)NB * NF * 256 * 4;       // 16.8 MB
    float* Xf = (float*)w;            w += SPECB;
    float* Ep = (float*)w;            w += (size_t)NB * 2 * FP * 4;     // 139 KB
    float* med = (float*)w;           w += 64;
    float* nrm = (float*)w;           w += (size_t)NB * NF * 4;
    float* vk = (float*)w;            w += 64;
    w = (char*)(((uintptr_t)w + 255) & ~(uintptr_t)255);
    int* rankpart = (int*)w;          w += (size_t)16640 * 17 * 4;      // 1.1 MB
    w = (char*)(((uintptr_t)w + 255) & ~(uintptr_t)255);
    float* Mpart = (float*)w;         w += (size_t)NB * FP * 34 * 4;    // 2.37 MB
    float* Lpart = (float*)w;         w += (size_t)NB * FP * 34 * 4;    // 2.37 MB
    w = (char*)(((uintptr_t)w + 255) & ~(uintptr_t)255);
    bf16* S = (bf16*)w;               w += (size_t)NB * FP * FP * 2;    // 75.8 MB
    bf16* Xb = (bf16*)w;              w += (size_t)NB * FP * 256 * 2;   // 8.9 MB
    bf16* K1 = (bf16*)w;              w += (size_t)NB * FP * 256 * 2;   // 8.9 MB
    bf16* Vt = (bf16*)w;              w += (size_t)NB * 256 * FP * 2;   // 8.9 MB
    bf16* Wk1 = (bf16*)w;             w += (size_t)256 * 256 * 2;
    bf16* Av = (bf16*)w;              w += (size_t)256 * 256 * 2;
    // Aliases (lifetimes disjoint):
    float2* Xc = (float2*)S;      // used only fftfwd -> xt (S written later)
    float* Ctxt = (float*)Xb;     // 16.8 MB over Xb+K1 (both dead after context)

    fftfwd_kernel<<<NB * NC + 256, 256, 0, stream>>>(x_in, W_K, W_V, Xc, Wk1, Av);
    xt_kernel<<<NB * 2 * 34, 256, 0, stream>>>(Xc, (float2*)Xf, Xb, Ep);
    kvvt_med_kernel<<<NB * 17 * 2 * 2 + NB * 9, 256, 0, stream>>>(
        Xb, Wk1, Av, b_K, b_V, Ep, K1, Vt, med);
    score_rank_kernel<<<NB * 17 * 34 + 65 * 17, 256, 0, stream>>>(
        Xb, K1, Ep, med, S, Mpart, Lpart, nrm, rankpart);
    rankreduce_kernel<<<65, 256, 0, stream>>>(rankpart, nrm, qpar, vk);
    context_kernel<<<NB * 65, 256, 0, stream>>>(S, Mpart, Lpart, Vt, (const float2*)Xf,
                                                nrm, vk, qpar, w_high, Ctxt);
    fft_inv_kernel<<<NB * NC, 256, 0, stream>>>(Ctxt, out);
}